// Round 10
// baseline (71.322 us; speedup 1.0000x reference)
//
#include <hip/hip_runtime.h>
#include <hip/hip_fp16.h>

#define D       128
#define NROWS   100000
#define NTILES  (NROWS / 16)   // 6250 exact
#define GRID_E  512            // 2 blocks/CU; 2048 waves grid-striding tiles

typedef __attribute__((ext_vector_type(8))) _Float16 f16x8;
typedef __attribute__((ext_vector_type(4))) float    f32x4;

union F16x8U { _Float16 h[8]; f16x8 v; };
union F32x4U { float f[4]; f32x4 v; };

typedef __attribute__((address_space(1))) const void gvoid;
typedef __attribute__((address_space(3))) void       lvoid;

// ---------------------------------------------------------------------------
// Kernel 0: metric -> fragment-ordered fp16 hi/lo B-fragments (contiguous:
// hi = 2048 16B-slots @0, lo = 2048 slots @32KB). Slot q = (kk*8+cf)*64+lane
// holds B[k0+j][col], col = cf*16+(lane&15), k0 = kk*32+(lane>>4)*8 — the
// 16x16x32 MFMA B-operand layout. fp16 split: M = Mh + Ml, resid ~2^-22.
// ---------------------------------------------------------------------------
__global__ __launch_bounds__(256) void convert_M16(
    const float* __restrict__ M, _Float16* __restrict__ mfrag)
{
    const int q    = blockIdx.x * 256 + threadIdx.x;  // [0, 2048)
    const int kk   = q >> 9;
    const int cf   = (q >> 6) & 7;
    const int lane = q & 63;
    const int col  = cf * 16 + (lane & 15);
    const int k0   = kk * 32 + (lane >> 4) * 8;

    F16x8U h, l;
    #pragma unroll
    for (int j = 0; j < 8; ++j) {
        float f = M[(k0 + j) * D + col];
        _Float16 hh = (_Float16)f;
        h.h[j] = hh;
        l.h[j] = (_Float16)(f - (float)hh);
    }
    *(f16x8*)(mfrag + q * 8)             = h.v;   // hi
    *(f16x8*)(mfrag + (2048 + q) * 8)    = l.v;   // lo
}

// ---------------------------------------------------------------------------
// Kernel 1: E' = E @ M (two-term fp16 MFMA), fp16 output in pi order,
// pi(c) = (c&15)*8 + (c>>4).
// Inverted staging: M-fragments (64 KB) live in LDS (staged once per block,
// single drain+barrier); E streams global->VGPR. Each WAVE independently
// processes 16-row tiles via grid-stride — NO barriers, NO LDS staging, no
// drains in the hot loop; 8 free-running waves/CU hide HBM latency.
// Per tile/wave: 8x dwordx4 A-loads, 64 conflict-free ds_read_b128 (B-frag
// slot = lane*16B), 64x2 MFMAs, 4x 16B pi-ordered stores.
// ---------------------------------------------------------------------------
__global__ __launch_bounds__(256, 2) void gemm_E_stream(
    const float* __restrict__ E, const _Float16* __restrict__ mfrag,
    _Float16* __restrict__ Ep)
{
    __shared__ _Float16 sm[4096 * 8];   // 64 KB: hi slots [0,2048), lo [2048,4096)

    const int tid  = threadIdx.x;
    const int lane = tid & 63;
    const int w    = tid >> 6;
    const int lrow = lane & 15;
    const int lk   = lane >> 4;

    // Stage all 4096 16B-slots of M-fragments, linear copy (wave-uniform
    // LDS base + lane*16; source linear -> layouts identical).
    #pragma unroll
    for (int it = 0; it < 16; ++it) {
        const int slot = it * 256 + w * 64 + lane;
        __builtin_amdgcn_global_load_lds(
            (gvoid*)(mfrag + slot * 8), (lvoid*)(sm + (it * 256 + w * 64) * 8),
            16, 0, 0);
    }
    asm volatile("s_waitcnt vmcnt(0)" ::: "memory");
    __syncthreads();

    const f16x8* Bh = (const f16x8*)sm;          // [q*64 + lane]
    const f16x8* Bl = (const f16x8*)sm + 2048;

    const int wgid = (int)blockIdx.x * 4 + w;    // 0..2047

    for (int tb = wgid; tb < NTILES; tb += GRID_E * 4) {
        const int row = tb * 16 + lrow;

        // A-loads for the whole tile up front (8 x 16B in flight).
        f32x4 ax[4], ay[4];
        #pragma unroll
        for (int kk = 0; kk < 4; ++kk) {
            const float* p = E + (size_t)row * D + kk * 32 + lk * 8;
            ax[kk] = *(const f32x4*)p;
            ay[kk] = *(const f32x4*)(p + 4);
        }

        f32x4 acc[8];
        #pragma unroll
        for (int cf = 0; cf < 8; ++cf) acc[cf] = (f32x4){0.f, 0.f, 0.f, 0.f};

        #pragma unroll
        for (int kk = 0; kk < 4; ++kk) {
            F16x8U a16;
            F32x4U x, y; x.v = ax[kk]; y.v = ay[kk];
            #pragma unroll
            for (int j = 0; j < 4; ++j) {
                a16.h[j]     = (_Float16)x.f[j];
                a16.h[j + 4] = (_Float16)y.f[j];
            }
            #pragma unroll
            for (int cf = 0; cf < 8; ++cf) {
                const int q = kk * 8 + cf;
                acc[cf] = __builtin_amdgcn_mfma_f32_16x16x32_f16(
                    a16.v, Bh[q * 64 + lane], acc[cf], 0, 0, 0);
                acc[cf] = __builtin_amdgcn_mfma_f32_16x16x32_f16(
                    a16.v, Bl[q * 64 + lane], acc[cf], 0, 0, 0);
            }
        }

        // Epilogue: C/D col = lane&15 = lrow, row = lk*4+i (m89-verified).
        // pi makes the 8 cf-values contiguous: Ep[row*128 + lrow*8 + cf].
        #pragma unroll
        for (int i = 0; i < 4; ++i) {
            const int ro = tb * 16 + lk * 4 + i;
            F16x8U o;
            #pragma unroll
            for (int cf = 0; cf < 8; ++cf) o.h[cf] = (_Float16)acc[cf][i];
            *(f16x8*)(Ep + (size_t)ro * D + lrow * 8) = o.v;
        }
    }
}

// ---------------------------------------------------------------------------
// Kernel 2: out[b] = sigmoid(2 * dot(Ep16[xs[b]], N[ys[b]]) - 1).
// Ep fp16 in pi order: lane l's slot j holds col c = l+16j, pairing with
// N[y][l+16j] (fp32 exact; 64B-coalesced per 16-lane group). 4 outputs per
// lane-group for load ILP (36 loads in flight); float4 output store.
// ---------------------------------------------------------------------------
__global__ __launch_bounds__(256) void gather_dotN(
    const int* __restrict__ xs, const int* __restrict__ ys,
    const _Float16* __restrict__ Ep, const float* __restrict__ N,
    float* __restrict__ out)
{
    const int tid = threadIdx.x;
    const int o0  = blockIdx.x * 64 + (tid >> 4) * 4;
    const int l   = tid & 15;

    const int4 x4 = *(const int4*)(xs + o0);
    const int4 y4 = *(const int4*)(ys + o0);
    const int xv[4] = {x4.x, x4.y, x4.z, x4.w};
    const int yv[4] = {y4.x, y4.y, y4.z, y4.w};

    float r[4];
    #pragma unroll
    for (int q = 0; q < 4; ++q) {
        const f16x8 a = *(const f16x8*)(Ep + (size_t)xv[q] * D + l * 8);
        const float* n = N + (size_t)yv[q] * D + l;
        float s = 0.f;
        #pragma unroll
        for (int j = 0; j < 8; ++j) s += (float)a[j] * n[16 * j];
        r[q] = s;
    }

    #pragma unroll
    for (int q = 0; q < 4; ++q) {
        r[q] += __shfl_xor(r[q], 1);
        r[q] += __shfl_xor(r[q], 2);
        r[q] += __shfl_xor(r[q], 4);
        r[q] += __shfl_xor(r[q], 8);
    }

    if (l == 0) {
        float4 v;
        v.x = 1.0f / (1.0f + __expf(1.0f - 2.0f * r[0]));
        v.y = 1.0f / (1.0f + __expf(1.0f - 2.0f * r[1]));
        v.z = 1.0f / (1.0f + __expf(1.0f - 2.0f * r[2]));
        v.w = 1.0f / (1.0f + __expf(1.0f - 2.0f * r[3]));
        *(float4*)(out + o0) = v;
    }
}

extern "C" void kernel_launch(void* const* d_in, const int* in_sizes, int n_in,
                              void* d_out, int out_size, void* d_ws, size_t ws_size,
                              hipStream_t stream) {
    const int*   xs     = (const int*)d_in[0];
    const int*   ys     = (const int*)d_in[1];
    const float* metric = (const float*)d_in[2];
    const float* EMBEDM = (const float*)d_in[3];
    const float* NEGEM  = (const float*)d_in[4];
    float*       out    = (float*)d_out;

    const int B = in_sizes[0];  // 262144

    // d_ws layout: Ep16 25.6MB @0, M-fragments (hi 32KB + lo 32KB) @64MB.
    char* ws = (char*)d_ws;
    _Float16* Ep    = (_Float16*)ws;
    _Float16* mfrag = (_Float16*)(ws + (64u << 20));

    convert_M16<<<8, 256, 0, stream>>>(metric, mfrag);

    gemm_E_stream<<<GRID_E, 256, 0, stream>>>(EMBEDM, mfrag, Ep);

    gather_dotN<<<B / 64, 256, 0, stream>>>(xs, ys, Ep, NEGEM, out);
}

// Round 11
// 70.929 us; speedup vs baseline: 1.0055x; 1.0055x over previous
//
#include <hip/hip_runtime.h>
#include <hip/hip_fp16.h>

#define D      128
#define NROWS  100000
#define EB     64                        // rows per E-block (4 x 16-row tiles)
#define NBE    ((NROWS + EB - 1) / EB)   // 1563
#define NBN    (NROWS / 16)              // 6250
#define NPREP  (NBE + NBN)               // 7813; bid%5==0 -> E (exactly 1563)

typedef __attribute__((ext_vector_type(8))) _Float16 f16x8;
typedef __attribute__((ext_vector_type(2))) _Float16 f16x2;
typedef __attribute__((ext_vector_type(4))) float    f32x4;

union F16x8U { _Float16 h[8]; f16x8 v; };
union F32x4U { float f[4]; f32x4 v; };

// ---------------------------------------------------------------------------
// Kernel 0: metric -> fragment-ordered fp16 hi/lo B-fragments (hi = slots
// [0,2048), lo = [2048,4096)). Slot q = (kk*8+cf)*64+lane holds B[k0+j][col],
// col = cf*16+(lane&15), k0 = kk*32+(lane>>4)*8 — the 16x16x32 MFMA
// B-operand layout. fp16 split: M = Mh + Ml, residual ~2^-22 |M|.
// ---------------------------------------------------------------------------
__global__ __launch_bounds__(256) void convert_M16(
    const float* __restrict__ M, _Float16* __restrict__ mfrag)
{
    const int q    = blockIdx.x * 256 + threadIdx.x;  // [0, 2048)
    const int kk   = q >> 9;
    const int cf   = (q >> 6) & 7;
    const int lane = q & 63;
    const int col  = cf * 16 + (lane & 15);
    const int k0   = kk * 32 + (lane >> 4) * 8;

    F16x8U h, l;
    #pragma unroll
    for (int j = 0; j < 8; ++j) {
        float f = M[(k0 + j) * D + col];
        _Float16 hh = (_Float16)f;
        h.h[j] = hh;
        l.h[j] = (_Float16)(f - (float)hh);
    }
    *(f16x8*)(mfrag + q * 8)          = h.v;   // hi
    *(f16x8*)(mfrag + (2048 + q) * 8) = l.v;   // lo
}

// ---------------------------------------------------------------------------
// Kernel 1 (fused prep, NO LDS, NO barriers anywhere):
//   bid % 5 == 0 -> E-GEMM block (64 rows), eid = bid/5      [1563 blocks]
//   else         -> N-convert block (16 rows), nid = bid-bid/5-1 [6250 blocks]
//
// E path: wave w owns 32 cols (cf = w*2+{0,1}) x 64 rows. Its 16 B-fragment
// slots load ONCE from L2 into 64 VGPR (asm-anchored). Then 4 x 16-row
// tiles: A direct global->VGPR (lane reads rows lane&15, k = kk*32 +
// (lane>>4)*8 — full 64B-line coverage), cvt to fp16, 16 MFMAs (two-term
// split), pi-ordered f16x2 stores. Free-running waves; N-waves on the same
// CU soak HBM during E load shadows.
//
// N path: row = nid*16 + (tid>>4); 8 dword loads at stride 64B (coalesced
// per 16-lane group) -> one pi-ordered 16B store. pi(c) = (c&15)*8 + (c>>4).
// ---------------------------------------------------------------------------
__global__ __launch_bounds__(256, 3) void prep_fused(
    const float* __restrict__ E, const float* __restrict__ N,
    const _Float16* __restrict__ mfrag,
    _Float16* __restrict__ Ep, _Float16* __restrict__ Np)
{
    const int tid = threadIdx.x;
    const int bid = (int)blockIdx.x;

    if (bid % 5 != 0) {
        // ---- N-convert ----
        const int nid = bid - bid / 5 - 1;              // 0..NBN-1
        const int l16 = tid & 15;
        const int row = nid * 16 + (tid >> 4);          // exact: NBN*16 = NROWS
        const float* src = N + (size_t)row * D + l16;
        F16x8U o;
        #pragma unroll
        for (int k = 0; k < 8; ++k) o.h[k] = (_Float16)src[16 * k];
        *(f16x8*)(Np + (size_t)row * D + l16 * 8) = o.v;
        return;
    }

    // ---- E-GEMM ----
    const int eid  = bid / 5;
    const int lane = tid & 63;
    const int w    = tid >> 6;
    const int rb   = eid * EB;
    const int lrow = lane & 15;
    const int lk   = lane >> 4;

    // Wave w's 16 B-fragment slots (cols w*32..+31), L2-hot, loaded once.
    f16x8 bh[4][2], bl[4][2];
    #pragma unroll
    for (int kk = 0; kk < 4; ++kk)
        #pragma unroll
        for (int cfl = 0; cfl < 2; ++cfl) {
            const int slot = (kk * 8 + w * 2 + cfl) * 64 + lane;
            bh[kk][cfl] = *(const f16x8*)(mfrag + slot * 8);
            bl[kk][cfl] = *(const f16x8*)(mfrag + (2048 + slot) * 8);
        }
    // Anchor: force B resident in regs here; nothing below can re-sink them.
    #pragma unroll
    for (int kk = 0; kk < 4; ++kk)
        #pragma unroll
        for (int cfl = 0; cfl < 2; ++cfl)
            asm volatile("" : "+v"(bh[kk][cfl]), "+v"(bl[kk][cfl]));

    #pragma unroll
    for (int rt = 0; rt < 4; ++rt) {
        const int row = rb + rt * 16 + lrow;
        const int gr  = min(row, NROWS - 1);            // tail clamp (reads)

        // A-loads: 8 x dwordx4, contiguous 32B per lane, full line coverage.
        f32x4 ax[4], ay[4];
        #pragma unroll
        for (int kk = 0; kk < 4; ++kk) {
            const float* p = E + (size_t)gr * D + kk * 32 + lk * 8;
            ax[kk] = *(const f32x4*)p;
            ay[kk] = *(const f32x4*)(p + 4);
        }

        f32x4 acc[2];
        acc[0] = (f32x4){0.f, 0.f, 0.f, 0.f};
        acc[1] = (f32x4){0.f, 0.f, 0.f, 0.f};

        #pragma unroll
        for (int kk = 0; kk < 4; ++kk) {
            F16x8U a16;
            F32x4U x, y; x.v = ax[kk]; y.v = ay[kk];
            #pragma unroll
            for (int j = 0; j < 4; ++j) {
                a16.h[j]     = (_Float16)x.f[j];
                a16.h[j + 4] = (_Float16)y.f[j];
            }
            #pragma unroll
            for (int cfl = 0; cfl < 2; ++cfl) {
                acc[cfl] = __builtin_amdgcn_mfma_f32_16x16x32_f16(
                    a16.v, bh[kk][cfl], acc[cfl], 0, 0, 0);
                acc[cfl] = __builtin_amdgcn_mfma_f32_16x16x32_f16(
                    a16.v, bl[kk][cfl], acc[cfl], 0, 0, 0);
            }
        }

        // Epilogue: C/D col = lane&15, row = (lane>>4)*4 + i (m89-verified).
        // Col c = w*32 + cfl*16 + lrow; pi(c) = lrow*8 + w*2 + cfl -> the two
        // cfl values are adjacent: one f16x2 (4B) store per i. The block's 4
        // waves jointly fill each 64B sector (w*2 offsets 0,2,4,6).
        #pragma unroll
        for (int i = 0; i < 4; ++i) {
            const int ro = rb + rt * 16 + lk * 4 + i;
            if (ro < NROWS) {
                f16x2 o;
                o[0] = (_Float16)acc[0][i];
                o[1] = (_Float16)acc[1][i];
                *(f16x2*)(Ep + (size_t)ro * D + lrow * 8 + w * 2) = o;
            }
        }
    }
}

// ---------------------------------------------------------------------------
// Kernel 2: out[b] = sigmoid(2 * dot(Ep[xs[b]], Np[ys[b]]) - 1).
// Both tables fp16 in pi order (dot is order-invariant). 16 lanes/output,
// 2 outputs per lane-group, one dwordx4 per table per output, fp32 accum.
// Proven 9.3 us in R7.
// ---------------------------------------------------------------------------
__global__ __launch_bounds__(256) void gather_dot16(
    const int* __restrict__ xs, const int* __restrict__ ys,
    const _Float16* __restrict__ Ep, const _Float16* __restrict__ Np,
    float* __restrict__ out)
{
    const int tid = threadIdx.x;
    const int o0  = blockIdx.x * 32 + (tid >> 4) * 2;
    const int l   = tid & 15;

    const int x0 = xs[o0], x1 = xs[o0 + 1];
    const int y0 = ys[o0], y1 = ys[o0 + 1];

    const f16x8 a0 = *(const f16x8*)(Ep + (size_t)x0 * D + l * 8);
    const f16x8 b0 = *(const f16x8*)(Np + (size_t)y0 * D + l * 8);
    const f16x8 a1 = *(const f16x8*)(Ep + (size_t)x1 * D + l * 8);
    const f16x8 b1 = *(const f16x8*)(Np + (size_t)y1 * D + l * 8);

    float r0 = 0.f, r1 = 0.f;
    #pragma unroll
    for (int j = 0; j < 8; ++j) {
        r0 += (float)a0[j] * (float)b0[j];
        r1 += (float)a1[j] * (float)b1[j];
    }

    r0 += __shfl_xor(r0, 1); r1 += __shfl_xor(r1, 1);
    r0 += __shfl_xor(r0, 2); r1 += __shfl_xor(r1, 2);
    r0 += __shfl_xor(r0, 4); r1 += __shfl_xor(r1, 4);
    r0 += __shfl_xor(r0, 8); r1 += __shfl_xor(r1, 8);

    if (l == 0) {
        float2 v;
        v.x = 1.0f / (1.0f + __expf(1.0f - 2.0f * r0));
        v.y = 1.0f / (1.0f + __expf(1.0f - 2.0f * r1));
        *(float2*)(out + o0) = v;
    }
}

extern "C" void kernel_launch(void* const* d_in, const int* in_sizes, int n_in,
                              void* d_out, int out_size, void* d_ws, size_t ws_size,
                              hipStream_t stream) {
    const int*   xs     = (const int*)d_in[0];
    const int*   ys     = (const int*)d_in[1];
    const float* metric = (const float*)d_in[2];
    const float* EMBEDM = (const float*)d_in[3];
    const float* NEGEM  = (const float*)d_in[4];
    float*       out    = (float*)d_out;

    const int B = in_sizes[0];  // 262144

    // d_ws layout: Ep16 25.6MB @0, Np16 25.6MB @32MB, M-fragments @64MB.
    char* ws = (char*)d_ws;
    _Float16* Ep    = (_Float16*)ws;
    _Float16* Np    = (_Float16*)(ws + (32u << 20));
    _Float16* mfrag = (_Float16*)(ws + (64u << 20));

    convert_M16<<<8, 256, 0, stream>>>(metric, mfrag);

    prep_fused<<<NPREP, 256, 0, stream>>>(EMBEDM, NEGEM, mfrag, Ep, Np);

    gather_dot16<<<B / 32, 256, 0, stream>>>(xs, ys, Ep, Np, out);
}